// Round 8
// baseline (238.091 us; speedup 1.0000x reference)
//
#include <hip/hip_runtime.h>
#include <cstdint>
#include <cstddef>

#define HB1 4096         // kC level-1 buckets (u>>19)
#define HB2 2048         // kC level-2 buckets ((u>>8)&0x7FF)
#define CMAX 21
#define IOU_T 0.5f
#define WPB 24           // waves (=blocks) per batch in kB

__device__ __forceinline__ float sl1(float x) {
    float ax = fabsf(x);
    return ax < 1.0f ? 0.5f * x * x : ax - 0.5f;
}

// async global->LDS, 16B per lane. dst is wave-uniform base; HW adds lane*16.
__device__ __forceinline__ void gld16(const float4* g, float4* l) {
    __builtin_amdgcn_global_load_lds((const __attribute__((address_space(1))) void*)g,
                                     (__attribute__((address_space(3))) void*)l, 16, 0, 0);
}

#define WAITVM(n) asm volatile("s_waitcnt vmcnt(" #n ")" ::: "memory")

// ---------------- Kernel A: per-truth argmax over prior slices (+ zero-init fold) ----------------
// UNCHANGED: exact f32 division here defines the bpi tie-breaking; kB/kC depend on it bit-exactly.
__global__ __launch_bounds__(256) void kA_best_prior(
    const float* __restrict__ targets, const float* __restrict__ priors,
    float* __restrict__ bpi_val, int* __restrict__ bpi_idx,
    int* __restrict__ num_pos_g, float* __restrict__ accB_g,
    float* __restrict__ acc_g, unsigned* __restrict__ done_g,
    int N, int NOBJ, int SLICES, int CHUNK, int B)
{
    const int s = blockIdx.x, b = blockIdx.y, t = threadIdx.x;
    __shared__ float tb[16 * 4];
    __shared__ float ta[16];
    __shared__ float wv[4 * 16];
    __shared__ int   wi[4 * 16];

    if (s == 0 && b == 0) {
        for (int q = t; q < B; q += 256) num_pos_g[q] = 0;
        for (int q = t; q < 2 * B; q += 256) accB_g[q] = 0.f;
        if (t < 4) acc_g[t] = 0.f;
        if (t == 0) *done_g = 0u;
    }

    if (t < 16) {
        if (t < NOBJ) {
            const float* tr = targets + ((size_t)b * NOBJ + t) * 5;
            float x0 = tr[0], y0 = tr[1], x1 = tr[2], y1 = tr[3];
            tb[t * 4 + 0] = x0; tb[t * 4 + 1] = y0;
            tb[t * 4 + 2] = x1; tb[t * 4 + 3] = y1;
            ta[t] = (x1 - x0) * (y1 - y0);
        } else {
            tb[t * 4 + 0] = 0.f; tb[t * 4 + 1] = 0.f;
            tb[t * 4 + 2] = 0.f; tb[t * 4 + 3] = 0.f;
            ta[t] = 0.f;
        }
    }
    __syncthreads();

    float bv[16]; int bi[16];
#pragma unroll
    for (int j = 0; j < 16; j++) { bv[j] = -1.0f; bi[j] = 0x7fffffff; }

    const int start = s * CHUNK;
    const int end = min(start + CHUNK, N);
    for (int i = start + t; i < end; i += 256) {
        float4 p = ((const float4*)priors)[i];
        float bx0 = p.x - p.z * 0.5f, by0 = p.y - p.w * 0.5f;
        float bx1 = p.x + p.z * 0.5f, by1 = p.y + p.w * 0.5f;
        float ab = (bx1 - bx0) * (by1 - by0);
#pragma unroll
        for (int j = 0; j < 16; j++) {
            float iw = fminf(tb[j * 4 + 2], bx1) - fmaxf(tb[j * 4 + 0], bx0);
            float ih = fminf(tb[j * 4 + 3], by1) - fmaxf(tb[j * 4 + 1], by0);
            iw = fmaxf(iw, 0.f); ih = fmaxf(ih, 0.f);
            float inter = iw * ih;
            float iou = inter / (ta[j] + ab - inter);
            if (iou > bv[j] || (iou == bv[j] && i < bi[j])) { bv[j] = iou; bi[j] = i; }
        }
    }

#pragma unroll
    for (int off = 32; off >= 1; off >>= 1) {
#pragma unroll
        for (int j = 0; j < 16; j++) {
            float v2 = __shfl_down(bv[j], off, 64);
            int   i2 = __shfl_down(bi[j], off, 64);
            if (v2 > bv[j] || (v2 == bv[j] && i2 < bi[j])) { bv[j] = v2; bi[j] = i2; }
        }
    }
    const int wid = t >> 6, lane = t & 63;
    if (lane == 0) {
#pragma unroll
        for (int j = 0; j < 16; j++) { wv[wid * 16 + j] = bv[j]; wi[wid * 16 + j] = bi[j]; }
    }
    __syncthreads();
    if (t < 16) {
        float v = wv[t]; int idx = wi[t];
#pragma unroll
        for (int w = 1; w < 4; w++) {
            float v2 = wv[w * 16 + t]; int i2 = wi[w * 16 + t];
            if (v2 > v || (v2 == v && i2 < idx)) { v = v2; idx = i2; }
        }
        if (t < NOBJ) {
            int o = (b * SLICES + s) * 16 + t;
            bpi_val[o] = v;
            bpi_idx[o] = idx;
        }
    }
}

// ---------------- Kernel B: per-wave decoupled pipeline (no barriers, counted vmcnt) ----------------
// R15: 64-thread single-wave blocks; each wave owns 64-row chunks (stride WPB) with a private
// 2x8KB LDS double buffer fed by global_load_lds. NO barriers anywhere: the lockstep
// round/burst structure of all previous variants (block barrier drains coupling every wave
// to the block's slowest cacheline) is the remaining theory for the 2TB/s effective-read
// plateau. Per-wave vmcnt is private -> waves drift freely.
// Counting discipline: every chunk issues EXACTLY 8 VMEM ops (6 conf gld_lds + 1 priors +
// 1 loc, address-CLAMPED instead of exec-guarded so the count never varies). Wait is the
// conservative vmcnt(8) when a next-chunk prefetch is in flight (the 8 newest = next chunk;
// everything older incl. stores completes), else vmcnt(0). Over-waiting stores is safe.
// LDS float4 layout per buffer (512 slots = 8KB): [0..383] conf (inst m writes m*64+lane),
// [384..447] priors, [448..511] loc. Conf rows read at float offset lane*21 (2-way bank
// alias = free). Per-row arithmetic identical to R14 -> absmax 0 expected.
#define IOU_STEP(j) { \
    float4 tj = tb4[j]; \
    float taj = (tj.z - tj.x) * (tj.w - tj.y); \
    float iw = fminf(tj.z, bx1) - fmaxf(tj.x, bx0); \
    float ih = fminf(tj.w, by1) - fmaxf(tj.y, by0); \
    iw = fmaxf(iw, 0.f); ih = fmaxf(ih, 0.f); \
    float inter = iw * ih; \
    float iou = inter * __builtin_amdgcn_rcpf(taj + ab - inter); \
    if (iou > bto) { bto = iou; bti = (j); } }

__global__ __launch_bounds__(64) void kB_main(
    const float* __restrict__ loc, const float* __restrict__ conf,
    const float* __restrict__ targets, const float* __restrict__ priors,
    const float* __restrict__ bpi_val, const int* __restrict__ bpi_idx,
    float* __restrict__ lc_out, int* __restrict__ num_pos, float* __restrict__ accB,
    int N, int NOBJ, int SLICES, int NCH)
{
    const int g = blockIdx.x;
    const int b = g / WPB;
    const int w0 = g % WPB;
    const int lane = threadIdx.x;          // 0..63

    __shared__ __align__(16) float4 buf[2][512];   // 2 x 8KB private to this wave
    __shared__ __align__(16) float tb[16 * 4];
    __shared__ float tl[16];
    __shared__ __align__(16) int bpi_s[16];

    const float* confB = conf + (size_t)b * N * CMAX;
    const float* locB  = loc + (size_t)b * N * 4;
    const float4* c4 = (const float4*)confB;
    const int n4c = (N * CMAX) >> 2;       // conf float4 count (N divisible by 4)

    // issue one chunk's 8 VMEM ops (counts are ALWAYS 8: clamped, never exec-guarded)
    auto issue = [&](int c, int p) {
        const int base = c * 336;          // 64 rows * 21 floats / 4
        float4* d = &buf[p][0];
#pragma unroll
        for (int m = 0; m < 6; m++) {
            int idx = min(base + m * 64 + lane, n4c - 1);
            gld16(c4 + idx, d + m * 64);   // uniform dst; HW adds lane*16
        }
        int r = min(c * 64 + lane, N - 1);
        gld16(((const float4*)priors) + r, d + 384);
        gld16(((const float4*)locB)  + r, d + 448);
    };

    // first two chunks in flight before anything else
    int c = w0;
    if (c < NCH) issue(c, 0);
    if (c + WPB < NCH) issue(c + WPB, 1);

    // stage truths + fold bpi slices (independent LDS region; lgkm-ordered within the wave)
    if (lane < 16) {
        if (lane < NOBJ) {
            const float* tr = targets + ((size_t)b * NOBJ + lane) * 5;
            tb[lane * 4 + 0] = tr[0]; tb[lane * 4 + 1] = tr[1];
            tb[lane * 4 + 2] = tr[2]; tb[lane * 4 + 3] = tr[3];
            tl[lane] = tr[4];
            float bv = -1.f; int bi = 0x7fffffff;
            for (int s2 = 0; s2 < SLICES; s2++) {
                int o = (b * SLICES + s2) * 16 + lane;
                float v = bpi_val[o]; int idx = bpi_idx[o];
                if (v > bv || (v == bv && idx < bi)) { bv = v; bi = idx; }
            }
            bpi_s[lane] = bi;
        } else {
            tb[lane * 4 + 0] = 0.f; tb[lane * 4 + 1] = 0.f;
            tb[lane * 4 + 2] = 0.f; tb[lane * 4 + 3] = 0.f;
            tl[lane] = 0.f; bpi_s[lane] = -1;
        }
    }
    __syncthreads();   // single wave: compiles to waitcnt; makes tb/tl/bpi_s visible to all lanes

    float ll = 0.f, plc = 0.f, np = 0.f;
    int p = 0;

    while (c < NCH) {
        // wait for chunk c's 8 loads. If a prefetch (8 newest) is in flight, vmcnt(8)
        // leaves exactly those; all older ops (chunk c + any stores) complete. Else drain.
        if (c + WPB < NCH) { WAITVM(8); } else { WAITVM(0); }

        const int i = c * 64 + lane;
        if (i < N) {
            const float* cr = (const float*)&buf[p][0] + lane * 21;
            float4 pp = buf[p][384 + lane];
            float4 myl = buf[p][448 + lane];

            float bx0 = pp.x - pp.z * 0.5f, by0 = pp.y - pp.w * 0.5f;
            float bx1 = pp.x + pp.z * 0.5f, by1 = pp.y + pp.w * 0.5f;
            float ab = (bx1 - bx0) * (by1 - by0);
            float bto = -1.f; int bti = 0;
            const float4* tb4 = (const float4*)tb;
            if (NOBJ == 16) {
#pragma unroll
                for (int j = 0; j < 16; j++) IOU_STEP(j);
            } else {
                for (int j = 0; j < NOBJ; j++) IOU_STEP(j);
            }
            const int4* bp4 = (const int4*)bpi_s;
#pragma unroll
            for (int jj = 0; jj < 4; jj++) {
                int4 q = bp4[jj];
                if (q.x == i) { bto = 2.0f; bti = jj * 4 + 0; }
                if (q.y == i) { bto = 2.0f; bti = jj * 4 + 1; }
                if (q.z == i) { bto = 2.0f; bti = jj * 4 + 2; }
                if (q.w == i) { bto = 2.0f; bti = jj * 4 + 3; }
            }
            bool pos = !(bto < IOU_T);
            if (pos) {
                float4 tj = tb4[bti];
                float rz = __builtin_amdgcn_rcpf(pp.z);
                float rw = __builtin_amdgcn_rcpf(pp.w);
                float gcx = ((tj.x + tj.z) * 0.5f - pp.x) * (10.0f * rz);
                float gcy = ((tj.y + tj.w) * 0.5f - pp.y) * (10.0f * rw);
                float gw = __logf((tj.z - tj.x) * rz) * 5.0f;
                float gh = __logf((tj.w - tj.y) * rw) * 5.0f;
                ll += sl1(myl.x - gcx) + sl1(myl.y - gcy) + sl1(myl.z - gw) + sl1(myl.w - gh);
                np += 1.f;
            }
            int cf = pos ? ((int)tl[bti] + 1) : 0;
            float m = cr[0];
#pragma unroll
            for (int q = 1; q < CMAX; q++) m = fmaxf(m, cr[q]);
            float ssum = 0.f;
#pragma unroll
            for (int q = 0; q < CMAX; q++) ssum += __expf(cr[q] - m);
            float lse = m + __logf(ssum);
            float lossc = lse - cr[cf];
            if (pos) plc += lossc;
            float lcv = pos ? 0.f : lossc;
            lcv = fmaxf(lcv, 0.f);
            lc_out[(size_t)b * N + i] = lcv;
        }

        // refill the just-consumed buffer with chunk c+2*WPB (overlaps next chunk's compute).
        // All ds_read results above are already consumed (in regs) before these LDS writes land.
        asm volatile("" ::: "memory");
        int c2 = c + 2 * WPB;
        if (c2 < NCH) issue(c2, p);
        p ^= 1;
        c += WPB;
    }

    // per-wave reduction + per-batch atomics
#pragma unroll
    for (int off = 32; off >= 1; off >>= 1) {
        ll  += __shfl_down(ll, off, 64);
        plc += __shfl_down(plc, off, 64);
        np  += __shfl_down(np, off, 64);
    }
    if (lane == 0) {
        atomicAdd(&accB[b * 2 + 0], ll);
        atomicAdd(&accB[b * 2 + 1], plc);
        atomicAdd(&num_pos[b], (int)np);
    }
}

// ---------------- Kernel C: 2-level radix select, hierarchical shuffle suffix-scan ----------------
__device__ __forceinline__ void wave_sufscan(int& c, float& s, int lane) {
#pragma unroll
    for (int off = 1; off < 64; off <<= 1) {
        int c2 = __shfl_down(c, off, 64);
        float s2 = __shfl_down(s, off, 64);
        if (lane + off < 64) { c += c2; s += s2; }
    }
}

__global__ __launch_bounds__(1024) void kC_topk(
    const float* __restrict__ lc, const int* __restrict__ num_pos,
    const float* __restrict__ accB,
    float* __restrict__ acc, unsigned* __restrict__ done_ctr,
    float* __restrict__ out, int N, int B)
{
    const int b = blockIdx.x, t = threadIdx.x;
    const int NT = 1024;
    const int wid = t >> 6, lane = t & 63;   // 16 waves
    __shared__ __align__(16) int   cnt[HB1];
    __shared__ __align__(16) float sm[HB1];
    __shared__ int   wc[16];
    __shared__ float ws[16];
    __shared__ int s_strad, s_krem;
    __shared__ float s_above;
    __shared__ int s_last;
    __shared__ float wsum[16], wsA[16], wsB[16];

    const int k = min(3 * num_pos[b], N - 1);
    const float* lcb = lc + (size_t)b * N;
    float total = 0.f;

    if (k > 0) {
        // ---- Level 1: bits [30:19] (4096 buckets), thread owns 4 ----
        ((int4*)cnt)[t] = make_int4(0, 0, 0, 0);
        ((float4*)sm)[t] = make_float4(0.f, 0.f, 0.f, 0.f);
        __syncthreads();
        const int n4 = N >> 2;
        const float4* lcb4 = (const float4*)lcb;
        for (int i = t; i < n4; i += NT) {
            float4 v = lcb4[i];
            { unsigned u = __float_as_uint(v.x) >> 19; atomicAdd(&cnt[u], 1); atomicAdd(&sm[u], v.x); }
            { unsigned u = __float_as_uint(v.y) >> 19; atomicAdd(&cnt[u], 1); atomicAdd(&sm[u], v.y); }
            { unsigned u = __float_as_uint(v.z) >> 19; atomicAdd(&cnt[u], 1); atomicAdd(&sm[u], v.z); }
            { unsigned u = __float_as_uint(v.w) >> 19; atomicAdd(&cnt[u], 1); atomicAdd(&sm[u], v.w); }
        }
        for (int i = (n4 << 2) + t; i < N; i += NT) {
            float v = lcb[i];
            unsigned u = __float_as_uint(v) >> 19;
            atomicAdd(&cnt[u], 1); atomicAdd(&sm[u], v);
        }
        __syncthreads();
        {
            int4  cv = ((const int4*)cnt)[t];
            float4 sv = ((const float4*)sm)[t];
            int   ci = cv.x + cv.y + cv.z + cv.w;
            float si = sv.x + sv.y + sv.z + sv.w;
            wave_sufscan(ci, si, lane);
            if (lane == 0) { wc[wid] = ci; ws[wid] = si; }
            __syncthreads();
            int cab = 0; float sab = 0.f;
            for (int w = wid + 1; w < 16; w++) { cab += wc[w]; sab += ws[w]; }
            int   i0c = ci + cab;          float f0 = si + sab;
            int   i1c = i0c - cv.x;        float f1 = f0 - sv.x;
            int   i2c = i1c - cv.y;        float f2 = f1 - sv.y;
            int   i3c = i2c - cv.z;        float f3 = f2 - sv.z;
            int   i4c = i3c - cv.w;
            if (i1c < k && k <= i0c) { s_strad = 4 * t + 0; s_krem = k - i1c; s_above = f1; }
            if (i2c < k && k <= i1c) { s_strad = 4 * t + 1; s_krem = k - i2c; s_above = f2; }
            if (i3c < k && k <= i2c) { s_strad = 4 * t + 2; s_krem = k - i3c; s_above = f3; }
            if (i4c < k && k <= i3c) { s_strad = 4 * t + 3; s_krem = k - i4c; s_above = f3 - sv.w; }
        }
        __syncthreads();
        const int s1 = s_strad, k2 = s_krem;
        total += s_above;

        // ---- Level 2: bits [18:8] (2048 buckets) within L1 bucket s1, thread owns 2 ----
        __syncthreads();
        ((int2*)cnt)[t] = make_int2(0, 0);
        ((float2*)sm)[t] = make_float2(0.f, 0.f);
        __syncthreads();
        for (int i = t; i < N; i += NT) {
            float v = lcb[i];
            unsigned u = __float_as_uint(v);
            if ((int)(u >> 19) == s1) {
                int q = (int)((u >> 8) & 0x7FF);
                atomicAdd(&cnt[q], 1); atomicAdd(&sm[q], v);
            }
        }
        __syncthreads();
        {
            int2  cv = ((const int2*)cnt)[t];
            float2 sv = ((const float2*)sm)[t];
            int   ci = cv.x + cv.y;
            float si = sv.x + sv.y;
            wave_sufscan(ci, si, lane);
            if (lane == 0) { wc[wid] = ci; ws[wid] = si; }
            __syncthreads();
            int cab = 0; float sab = 0.f;
            for (int w = wid + 1; w < 16; w++) { cab += wc[w]; sab += ws[w]; }
            int   i0c = ci + cab;       float f0 = si + sab;
            int   i1c = i0c - cv.x;     float f1 = f0 - sv.x;
            int   i2c = i1c - cv.y;
            if (i1c < k2 && k2 <= i0c) { s_strad = 2 * t + 0; s_krem = k2 - i1c; s_above = f1; }
            if (i2c < k2 && k2 <= i1c) { s_strad = 2 * t + 1; s_krem = k2 - i2c; s_above = f1 - sv.y; }
        }
        __syncthreads();
        const int s2 = s_strad, krem = s_krem;
        total += s_above;
        float tval = __uint_as_float((((unsigned)s1) << 19) | (((unsigned)s2) << 8));
        total += (float)krem * tval;
    }

    // contribute + last-block finalize
    if (t == 0) {
        if (k > 0) atomicAdd(&acc[1], total);
        __threadfence();
        unsigned old = atomicAdd(done_ctr, 1u);
        s_last = (old == (unsigned)gridDim.x - 1u) ? 1 : 0;
    }
    __syncthreads();
    if (s_last) {
        __threadfence();
        float vn = 0.f, va = 0.f, vb = 0.f;
        for (int q = t; q < B; q += NT) {
            vn += (float)num_pos[q];
            va += accB[q * 2 + 0];
            vb += accB[q * 2 + 1];
        }
#pragma unroll
        for (int off = 32; off >= 1; off >>= 1) {
            vn += __shfl_down(vn, off, 64);
            va += __shfl_down(va, off, 64);
            vb += __shfl_down(vb, off, 64);
        }
        if (lane == 0) { wsum[wid] = vn; wsA[wid] = va; wsB[wid] = vb; }
        __syncthreads();
        if (t == 0) {
            float n = 0.f, a = 0.f, bsum = 0.f;
#pragma unroll
            for (int w = 0; w < 16; w++) { n += wsum[w]; a += wsA[w]; bsum += wsB[w]; }
            float l2 = atomicAdd(&acc[1], 0.0f);
            out[0] = a / n;
            out[1] = (bsum + l2) / n;
        }
    }
}

extern "C" void kernel_launch(void* const* d_in, const int* in_sizes, int n_in,
                              void* d_out, int out_size, void* d_ws, size_t ws_size,
                              hipStream_t stream)
{
    const float* loc     = (const float*)d_in[0];
    const float* conf    = (const float*)d_in[1];
    const float* targets = (const float*)d_in[2];
    const float* priors  = (const float*)d_in[3];
    float* out = (float*)d_out;

    const int N = in_sizes[3] / 4;
    const int BN = in_sizes[0] / 4;
    const int B = BN / N;
    const int NOBJ = in_sizes[2] / (B * 5);
    const int SLICES = 8;
    const int CHUNK = (N + SLICES - 1) / SLICES;
    const int NCH = (N + 63) / 64;       // 64-row chunks per batch

    // workspace layout
    char* w = (char*)d_ws;
    float*    lc_ws   = (float*)w;                         size_t off = (size_t)BN * 4;
    float*    bpi_val = (float*)(w + off);                 off += (size_t)B * SLICES * 16 * 4;
    int*      bpi_idx = (int*)(w + off);                   off += (size_t)B * SLICES * 16 * 4;
    int*      num_pos = (int*)(w + off);                   off += (size_t)B * 4;
    float*    accB    = (float*)(w + off);                 off += (size_t)B * 2 * 4;
    float*    acc     = (float*)(w + off);                 off += 16;
    unsigned* done    = (unsigned*)(w + off);              off += 16;

    dim3 gA(SLICES, B);
    kA_best_prior<<<gA, 256, 0, stream>>>(targets, priors, bpi_val, bpi_idx,
                                          num_pos, accB, acc, done, N, NOBJ, SLICES, CHUNK, B);

    kB_main<<<B * WPB, 64, 0, stream>>>(loc, conf, targets, priors, bpi_val, bpi_idx,
                                        lc_ws, num_pos, accB, N, NOBJ, SLICES, NCH);

    kC_topk<<<B, 1024, 0, stream>>>(lc_ws, num_pos, accB, acc, done, out, N, B);
}

// Round 9
// 229.371 us; speedup vs baseline: 1.0380x; 1.0380x over previous
//
#include <hip/hip_runtime.h>
#include <cstdint>
#include <cstddef>

#define HB1 4096         // kC level-1 buckets (u>>19)
#define HB2 2048         // kC level-2 buckets ((u>>8)&0x7FF)
#define CMAX 21
#define IOU_T 0.5f

__device__ __forceinline__ float sl1(float x) {
    float ax = fabsf(x);
    return ax < 1.0f ? 0.5f * x * x : ax - 0.5f;
}

// ---------------- Kernel A: per-truth argmax over prior slices (+ zero-init fold) ----------------
// UNCHANGED: exact f32 division here defines the bpi tie-breaking; kB/kC depend on it bit-exactly.
__global__ __launch_bounds__(256) void kA_best_prior(
    const float* __restrict__ targets, const float* __restrict__ priors,
    float* __restrict__ bpi_val, int* __restrict__ bpi_idx,
    int* __restrict__ num_pos_g, float* __restrict__ accB_g,
    float* __restrict__ acc_g, unsigned* __restrict__ done_g,
    int N, int NOBJ, int SLICES, int CHUNK, int B)
{
    const int s = blockIdx.x, b = blockIdx.y, t = threadIdx.x;
    __shared__ float tb[16 * 4];
    __shared__ float ta[16];
    __shared__ float wv[4 * 16];
    __shared__ int   wi[4 * 16];

    if (s == 0 && b == 0) {
        for (int q = t; q < B; q += 256) num_pos_g[q] = 0;
        for (int q = t; q < 2 * B; q += 256) accB_g[q] = 0.f;
        if (t < 4) acc_g[t] = 0.f;
        if (t == 0) *done_g = 0u;
    }

    if (t < 16) {
        if (t < NOBJ) {
            const float* tr = targets + ((size_t)b * NOBJ + t) * 5;
            float x0 = tr[0], y0 = tr[1], x1 = tr[2], y1 = tr[3];
            tb[t * 4 + 0] = x0; tb[t * 4 + 1] = y0;
            tb[t * 4 + 2] = x1; tb[t * 4 + 3] = y1;
            ta[t] = (x1 - x0) * (y1 - y0);
        } else {
            tb[t * 4 + 0] = 0.f; tb[t * 4 + 1] = 0.f;
            tb[t * 4 + 2] = 0.f; tb[t * 4 + 3] = 0.f;
            ta[t] = 0.f;
        }
    }
    __syncthreads();

    float bv[16]; int bi[16];
#pragma unroll
    for (int j = 0; j < 16; j++) { bv[j] = -1.0f; bi[j] = 0x7fffffff; }

    const int start = s * CHUNK;
    const int end = min(start + CHUNK, N);
    for (int i = start + t; i < end; i += 256) {
        float4 p = ((const float4*)priors)[i];
        float bx0 = p.x - p.z * 0.5f, by0 = p.y - p.w * 0.5f;
        float bx1 = p.x + p.z * 0.5f, by1 = p.y + p.w * 0.5f;
        float ab = (bx1 - bx0) * (by1 - by0);
#pragma unroll
        for (int j = 0; j < 16; j++) {
            float iw = fminf(tb[j * 4 + 2], bx1) - fmaxf(tb[j * 4 + 0], bx0);
            float ih = fminf(tb[j * 4 + 3], by1) - fmaxf(tb[j * 4 + 1], by0);
            iw = fmaxf(iw, 0.f); ih = fmaxf(ih, 0.f);
            float inter = iw * ih;
            float iou = inter / (ta[j] + ab - inter);
            if (iou > bv[j] || (iou == bv[j] && i < bi[j])) { bv[j] = iou; bi[j] = i; }
        }
    }

#pragma unroll
    for (int off = 32; off >= 1; off >>= 1) {
#pragma unroll
        for (int j = 0; j < 16; j++) {
            float v2 = __shfl_down(bv[j], off, 64);
            int   i2 = __shfl_down(bi[j], off, 64);
            if (v2 > bv[j] || (v2 == bv[j] && i2 < bi[j])) { bv[j] = v2; bi[j] = i2; }
        }
    }
    const int wid = t >> 6, lane = t & 63;
    if (lane == 0) {
#pragma unroll
        for (int j = 0; j < 16; j++) { wv[wid * 16 + j] = bv[j]; wi[wid * 16 + j] = bi[j]; }
    }
    __syncthreads();
    if (t < 16) {
        float v = wv[t]; int idx = wi[t];
#pragma unroll
        for (int w = 1; w < 4; w++) {
            float v2 = wv[w * 16 + t]; int i2 = wi[w * 16 + t];
            if (v2 > v || (v2 == v && i2 < idx)) { v = v2; idx = i2; }
        }
        if (t < NOBJ) {
            int o = (b * SLICES + s) * 16 + t;
            bpi_val[o] = v;
            bpi_idx[o] = idx;
        }
    }
}

// ---------------- Kernel B: 512-row tiles, 2 independent rows per thread (ILP) ----------------
// R16: every prior variant gave each thread ONE row per tile -> the ~350-cycle serial
// softmax chain (20 dep fmax + exp-sum + log) ran with zero ILP; VALUBusy pinned at ~30%
// regardless of waves (R10), barriers (R12), staging path (R14), decoupling (R15).
// This round: TILE=512 rows, 256 threads, thread t computes rows i0+t AND i0+256+t --
// two independent chains that interleave in each other's latency shadow.
// Single 43KB LDS buffer (3 blocks/CU = 12 waves/CU, same as R14); reg-staged prefetch
// (11 conf float4 + 2x priors/loc) issued BEFORE compute (T14); 2 barriers per 512 rows
// (half R14's rate). Per-row arithmetic byte-identical -> absmax 0 expected.
#define IOU_STEP2(j, P, BX0, BY0, BX1, BY1, AB, BTO, BTI) { \
    float4 tj = tb4[j]; \
    float taj = (tj.z - tj.x) * (tj.w - tj.y); \
    float iw = fminf(tj.z, BX1) - fmaxf(tj.x, BX0); \
    float ih = fminf(tj.w, BY1) - fmaxf(tj.y, BY0); \
    iw = fmaxf(iw, 0.f); ih = fmaxf(ih, 0.f); \
    float inter = iw * ih; \
    float iou = inter * __builtin_amdgcn_rcpf(taj + AB - inter); \
    if (iou > BTO) { BTO = iou; BTI = (j); } }

__global__ __launch_bounds__(256, 3) void kB_main(
    const float* __restrict__ loc, const float* __restrict__ conf,
    const float* __restrict__ targets, const float* __restrict__ priors,
    const float* __restrict__ bpi_val, const int* __restrict__ bpi_idx,
    float* __restrict__ lc_out, int* __restrict__ num_pos, float* __restrict__ accB,
    int N, int NOBJ, int SLICES, int TPB, int BPB)
{
    const int g = blockIdx.x;
    const int b = g / BPB;
    const int j0 = g % BPB;
    const int t = threadIdx.x;
    const int wid = t >> 6, lane = t & 63;

    __shared__ __align__(16) float buf[512 * CMAX];   // 43008 B, single buffer
    __shared__ __align__(16) float tb[16 * 4];
    __shared__ float tl[16];
    __shared__ __align__(16) int bpi_s[16];
    __shared__ float wred[4 * 3];

    if (t < 16) {
        if (t < NOBJ) {
            const float* tr = targets + ((size_t)b * NOBJ + t) * 5;
            tb[t * 4 + 0] = tr[0]; tb[t * 4 + 1] = tr[1];
            tb[t * 4 + 2] = tr[2]; tb[t * 4 + 3] = tr[3];
            tl[t] = tr[4];
            float bv = -1.f; int bi = 0x7fffffff;
            for (int s2 = 0; s2 < SLICES; s2++) {
                int o = (b * SLICES + s2) * 16 + t;
                float v = bpi_val[o]; int idx = bpi_idx[o];
                if (v > bv || (v == bv && idx < bi)) { bv = v; bi = idx; }
            }
            bpi_s[t] = bi;
        } else {
            tb[t * 4 + 0] = 0.f; tb[t * 4 + 1] = 0.f; tb[t * 4 + 2] = 0.f; tb[t * 4 + 3] = 0.f;
            tl[t] = 0.f; bpi_s[t] = -1;
        }
    }

    const float* confB = conf + (size_t)b * N * CMAX;
    const float* locB  = loc + (size_t)b * N * 4;

    float4 r0, r1, r2, r3, r4, r5, r6, r7, r8, r9, r10;
    float4 pr0, pr1, ld0, ld1;

    auto stage = [&](int xx) {
        int i0s = xx * 512;
        int rows_s = min(512, N - i0s);
        int nf4s = (rows_s * CMAX) >> 2;          // rows_s divisible by 4 -> exact
        const float4* s4 = (const float4*)(confB + (size_t)i0s * CMAX);
        if (t + 0    < nf4s) r0  = s4[t + 0];
        if (t + 256  < nf4s) r1  = s4[t + 256];
        if (t + 512  < nf4s) r2  = s4[t + 512];
        if (t + 768  < nf4s) r3  = s4[t + 768];
        if (t + 1024 < nf4s) r4  = s4[t + 1024];
        if (t + 1280 < nf4s) r5  = s4[t + 1280];
        if (t + 1536 < nf4s) r6  = s4[t + 1536];
        if (t + 1792 < nf4s) r7  = s4[t + 1792];
        if (t + 2048 < nf4s) r8  = s4[t + 2048];
        if (t + 2304 < nf4s) r9  = s4[t + 2304];
        if (t + 2560 < nf4s) r10 = s4[t + 2560];
        if (t < rows_s) {
            pr0 = ((const float4*)priors)[i0s + t];
            ld0 = ((const float4*)locB)[i0s + t];
        }
        if (256 + t < rows_s) {
            pr1 = ((const float4*)priors)[i0s + 256 + t];
            ld1 = ((const float4*)locB)[i0s + 256 + t];
        }
    };

    float ll = 0.f, plc = 0.f, np = 0.f;
    int x = j0;
    if (x < TPB) stage(x);

    while (x < TPB) {
        const int i0 = x * 512;
        const int rows = min(512, N - i0);
        const int nf4 = (rows * CMAX) >> 2;

        __syncthreads();                       // previous tile's readers done; LDS reusable

        float4 myp0 = pr0, myl0 = ld0, myp1 = pr1, myl1 = ld1;
        float4* bp4f = (float4*)buf;
        if (t + 0    < nf4) bp4f[t + 0]    = r0;
        if (t + 256  < nf4) bp4f[t + 256]  = r1;
        if (t + 512  < nf4) bp4f[t + 512]  = r2;
        if (t + 768  < nf4) bp4f[t + 768]  = r3;
        if (t + 1024 < nf4) bp4f[t + 1024] = r4;
        if (t + 1280 < nf4) bp4f[t + 1280] = r5;
        if (t + 1536 < nf4) bp4f[t + 1536] = r6;
        if (t + 1792 < nf4) bp4f[t + 1792] = r7;
        if (t + 2048 < nf4) bp4f[t + 2048] = r8;
        if (t + 2304 < nf4) bp4f[t + 2304] = r9;
        if (t + 2560 < nf4) bp4f[t + 2560] = r10;
        __syncthreads();                       // staged tile visible

        int xn = x + BPB;
        if (xn < TPB) stage(xn);               // prefetch next tile into regs (T14)

        const bool a0 = (t < rows);
        const bool a1 = (256 + t < rows);
        const int i1 = i0 + t, i2 = i0 + 256 + t;
        const float4* tb4 = (const float4*)tb;
        const int4* bp4 = (const int4*)bpi_s;

        // ---- two independent per-row pipelines; compiler interleaves the chains ----
        float bto0 = -1.f, bto1 = -1.f; int bti0 = 0, bti1 = 0;
        float bx00 = 0, by00 = 0, bx10 = 0, by10 = 0, ab0 = 0;
        float bx01 = 0, by01 = 0, bx11 = 0, by11 = 0, ab1 = 0;
        if (a0) {
            bx00 = myp0.x - myp0.z * 0.5f; by00 = myp0.y - myp0.w * 0.5f;
            bx10 = myp0.x + myp0.z * 0.5f; by10 = myp0.y + myp0.w * 0.5f;
            ab0 = (bx10 - bx00) * (by10 - by00);
        }
        if (a1) {
            bx01 = myp1.x - myp1.z * 0.5f; by01 = myp1.y - myp1.w * 0.5f;
            bx11 = myp1.x + myp1.z * 0.5f; by11 = myp1.y + myp1.w * 0.5f;
            ab1 = (bx11 - bx01) * (by11 - by01);
        }
#pragma unroll
        for (int j = 0; j < 16; j++) {
            IOU_STEP2(j, 0, bx00, by00, bx10, by10, ab0, bto0, bti0);
            IOU_STEP2(j, 1, bx01, by01, bx11, by11, ab1, bto1, bti1);
        }
#pragma unroll
        for (int jj = 0; jj < 4; jj++) {
            int4 q = bp4[jj];
            if (q.x == i1) { bto0 = 2.0f; bti0 = jj * 4 + 0; }
            if (q.y == i1) { bto0 = 2.0f; bti0 = jj * 4 + 1; }
            if (q.z == i1) { bto0 = 2.0f; bti0 = jj * 4 + 2; }
            if (q.w == i1) { bto0 = 2.0f; bti0 = jj * 4 + 3; }
            if (q.x == i2) { bto1 = 2.0f; bti1 = jj * 4 + 0; }
            if (q.y == i2) { bto1 = 2.0f; bti1 = jj * 4 + 1; }
            if (q.z == i2) { bto1 = 2.0f; bti1 = jj * 4 + 2; }
            if (q.w == i2) { bto1 = 2.0f; bti1 = jj * 4 + 3; }
        }
        bool pos0 = a0 && !(bto0 < IOU_T);
        bool pos1 = a1 && !(bto1 < IOU_T);
        if (pos0) {
            float4 tj = tb4[bti0];
            float rz = __builtin_amdgcn_rcpf(myp0.z);
            float rw = __builtin_amdgcn_rcpf(myp0.w);
            float gcx = ((tj.x + tj.z) * 0.5f - myp0.x) * (10.0f * rz);
            float gcy = ((tj.y + tj.w) * 0.5f - myp0.y) * (10.0f * rw);
            float gw = __logf((tj.z - tj.x) * rz) * 5.0f;
            float gh = __logf((tj.w - tj.y) * rw) * 5.0f;
            ll += sl1(myl0.x - gcx) + sl1(myl0.y - gcy) + sl1(myl0.z - gw) + sl1(myl0.w - gh);
            np += 1.f;
        }
        if (pos1) {
            float4 tj = tb4[bti1];
            float rz = __builtin_amdgcn_rcpf(myp1.z);
            float rw = __builtin_amdgcn_rcpf(myp1.w);
            float gcx = ((tj.x + tj.z) * 0.5f - myp1.x) * (10.0f * rz);
            float gcy = ((tj.y + tj.w) * 0.5f - myp1.y) * (10.0f * rw);
            float gw = __logf((tj.z - tj.x) * rz) * 5.0f;
            float gh = __logf((tj.w - tj.y) * rw) * 5.0f;
            ll += sl1(myl1.x - gcx) + sl1(myl1.y - gcy) + sl1(myl1.z - gw) + sl1(myl1.w - gh);
            np += 1.f;
        }
        {
            int cf0 = pos0 ? ((int)tl[bti0] + 1) : 0;
            int cf1 = pos1 ? ((int)tl[bti1] + 1) : 0;
            const float* cr0 = buf + t * CMAX;
            const float* cr1 = buf + (256 + t) * CMAX;
            // interleaved max chains (independent)
            float m0 = cr0[0], m1 = cr1[0];
#pragma unroll
            for (int c = 1; c < CMAX; c++) { m0 = fmaxf(m0, cr0[c]); m1 = fmaxf(m1, cr1[c]); }
            float s0 = 0.f, s1 = 0.f;
#pragma unroll
            for (int c = 0; c < CMAX; c++) { s0 += __expf(cr0[c] - m0); s1 += __expf(cr1[c] - m1); }
            float lse0 = m0 + __logf(s0);
            float lse1 = m1 + __logf(s1);
            if (a0) {
                float lossc = lse0 - cr0[cf0];
                if (pos0) plc += lossc;
                float lcv = pos0 ? 0.f : lossc;
                lc_out[(size_t)b * N + i1] = fmaxf(lcv, 0.f);
            }
            if (a1) {
                float lossc = lse1 - cr1[cf1];
                if (pos1) plc += lossc;
                float lcv = pos1 ? 0.f : lossc;
                lc_out[(size_t)b * N + i2] = fmaxf(lcv, 0.f);
            }
        }
        x = xn;
    }

#pragma unroll
    for (int off = 32; off >= 1; off >>= 1) {
        ll  += __shfl_down(ll, off, 64);
        plc += __shfl_down(plc, off, 64);
        np  += __shfl_down(np, off, 64);
    }
    if (lane == 0) { wred[wid * 3 + 0] = ll; wred[wid * 3 + 1] = plc; wred[wid * 3 + 2] = np; }
    __syncthreads();
    if (t == 0) {
        float a0r = 0.f, a1r = 0.f, a2r = 0.f;
#pragma unroll
        for (int w = 0; w < 4; w++) { a0r += wred[w * 3 + 0]; a1r += wred[w * 3 + 1]; a2r += wred[w * 3 + 2]; }
        atomicAdd(&accB[b * 2 + 0], a0r);
        atomicAdd(&accB[b * 2 + 1], a1r);
        atomicAdd(&num_pos[b], (int)a2r);
    }
}

// ---------------- Kernel C: 2-level radix select, hierarchical shuffle suffix-scan ----------------
__device__ __forceinline__ void wave_sufscan(int& c, float& s, int lane) {
#pragma unroll
    for (int off = 1; off < 64; off <<= 1) {
        int c2 = __shfl_down(c, off, 64);
        float s2 = __shfl_down(s, off, 64);
        if (lane + off < 64) { c += c2; s += s2; }
    }
}

__global__ __launch_bounds__(1024) void kC_topk(
    const float* __restrict__ lc, const int* __restrict__ num_pos,
    const float* __restrict__ accB,
    float* __restrict__ acc, unsigned* __restrict__ done_ctr,
    float* __restrict__ out, int N, int B)
{
    const int b = blockIdx.x, t = threadIdx.x;
    const int NT = 1024;
    const int wid = t >> 6, lane = t & 63;   // 16 waves
    __shared__ __align__(16) int   cnt[HB1];
    __shared__ __align__(16) float sm[HB1];
    __shared__ int   wc[16];
    __shared__ float ws[16];
    __shared__ int s_strad, s_krem;
    __shared__ float s_above;
    __shared__ int s_last;
    __shared__ float wsum[16], wsA[16], wsB[16];

    const int k = min(3 * num_pos[b], N - 1);
    const float* lcb = lc + (size_t)b * N;
    float total = 0.f;

    if (k > 0) {
        // ---- Level 1: bits [30:19] (4096 buckets), thread owns 4 ----
        ((int4*)cnt)[t] = make_int4(0, 0, 0, 0);
        ((float4*)sm)[t] = make_float4(0.f, 0.f, 0.f, 0.f);
        __syncthreads();
        const int n4 = N >> 2;
        const float4* lcb4 = (const float4*)lcb;
        for (int i = t; i < n4; i += NT) {
            float4 v = lcb4[i];
            { unsigned u = __float_as_uint(v.x) >> 19; atomicAdd(&cnt[u], 1); atomicAdd(&sm[u], v.x); }
            { unsigned u = __float_as_uint(v.y) >> 19; atomicAdd(&cnt[u], 1); atomicAdd(&sm[u], v.y); }
            { unsigned u = __float_as_uint(v.z) >> 19; atomicAdd(&cnt[u], 1); atomicAdd(&sm[u], v.z); }
            { unsigned u = __float_as_uint(v.w) >> 19; atomicAdd(&cnt[u], 1); atomicAdd(&sm[u], v.w); }
        }
        for (int i = (n4 << 2) + t; i < N; i += NT) {
            float v = lcb[i];
            unsigned u = __float_as_uint(v) >> 19;
            atomicAdd(&cnt[u], 1); atomicAdd(&sm[u], v);
        }
        __syncthreads();
        {
            int4  cv = ((const int4*)cnt)[t];
            float4 sv = ((const float4*)sm)[t];
            int   ci = cv.x + cv.y + cv.z + cv.w;
            float si = sv.x + sv.y + sv.z + sv.w;
            wave_sufscan(ci, si, lane);
            if (lane == 0) { wc[wid] = ci; ws[wid] = si; }
            __syncthreads();
            int cab = 0; float sab = 0.f;
            for (int w = wid + 1; w < 16; w++) { cab += wc[w]; sab += ws[w]; }
            int   i0c = ci + cab;          float f0 = si + sab;
            int   i1c = i0c - cv.x;        float f1 = f0 - sv.x;
            int   i2c = i1c - cv.y;        float f2 = f1 - sv.y;
            int   i3c = i2c - cv.z;        float f3 = f2 - sv.z;
            int   i4c = i3c - cv.w;
            if (i1c < k && k <= i0c) { s_strad = 4 * t + 0; s_krem = k - i1c; s_above = f1; }
            if (i2c < k && k <= i1c) { s_strad = 4 * t + 1; s_krem = k - i2c; s_above = f2; }
            if (i3c < k && k <= i2c) { s_strad = 4 * t + 2; s_krem = k - i3c; s_above = f3; }
            if (i4c < k && k <= i3c) { s_strad = 4 * t + 3; s_krem = k - i4c; s_above = f3 - sv.w; }
        }
        __syncthreads();
        const int s1 = s_strad, k2 = s_krem;
        total += s_above;

        // ---- Level 2: bits [18:8] (2048 buckets) within L1 bucket s1, thread owns 2 ----
        __syncthreads();
        ((int2*)cnt)[t] = make_int2(0, 0);
        ((float2*)sm)[t] = make_float2(0.f, 0.f);
        __syncthreads();
        for (int i = t; i < N; i += NT) {
            float v = lcb[i];
            unsigned u = __float_as_uint(v);
            if ((int)(u >> 19) == s1) {
                int q = (int)((u >> 8) & 0x7FF);
                atomicAdd(&cnt[q], 1); atomicAdd(&sm[q], v);
            }
        }
        __syncthreads();
        {
            int2  cv = ((const int2*)cnt)[t];
            float2 sv = ((const float2*)sm)[t];
            int   ci = cv.x + cv.y;
            float si = sv.x + sv.y;
            wave_sufscan(ci, si, lane);
            if (lane == 0) { wc[wid] = ci; ws[wid] = si; }
            __syncthreads();
            int cab = 0; float sab = 0.f;
            for (int w = wid + 1; w < 16; w++) { cab += wc[w]; sab += ws[w]; }
            int   i0c = ci + cab;       float f0 = si + sab;
            int   i1c = i0c - cv.x;     float f1 = f0 - sv.x;
            int   i2c = i1c - cv.y;
            if (i1c < k2 && k2 <= i0c) { s_strad = 2 * t + 0; s_krem = k2 - i1c; s_above = f1; }
            if (i2c < k2 && k2 <= i1c) { s_strad = 2 * t + 1; s_krem = k2 - i2c; s_above = f1 - sv.y; }
        }
        __syncthreads();
        const int s2 = s_strad, krem = s_krem;
        total += s_above;
        float tval = __uint_as_float((((unsigned)s1) << 19) | (((unsigned)s2) << 8));
        total += (float)krem * tval;
    }

    // contribute + last-block finalize
    if (t == 0) {
        if (k > 0) atomicAdd(&acc[1], total);
        __threadfence();
        unsigned old = atomicAdd(done_ctr, 1u);
        s_last = (old == (unsigned)gridDim.x - 1u) ? 1 : 0;
    }
    __syncthreads();
    if (s_last) {
        __threadfence();
        float vn = 0.f, va = 0.f, vb = 0.f;
        for (int q = t; q < B; q += NT) {
            vn += (float)num_pos[q];
            va += accB[q * 2 + 0];
            vb += accB[q * 2 + 1];
        }
#pragma unroll
        for (int off = 32; off >= 1; off >>= 1) {
            vn += __shfl_down(vn, off, 64);
            va += __shfl_down(va, off, 64);
            vb += __shfl_down(vb, off, 64);
        }
        if (lane == 0) { wsum[wid] = vn; wsA[wid] = va; wsB[wid] = vb; }
        __syncthreads();
        if (t == 0) {
            float n = 0.f, a = 0.f, bsum = 0.f;
#pragma unroll
            for (int w = 0; w < 16; w++) { n += wsum[w]; a += wsA[w]; bsum += wsB[w]; }
            float l2 = atomicAdd(&acc[1], 0.0f);
            out[0] = a / n;
            out[1] = (bsum + l2) / n;
        }
    }
}

extern "C" void kernel_launch(void* const* d_in, const int* in_sizes, int n_in,
                              void* d_out, int out_size, void* d_ws, size_t ws_size,
                              hipStream_t stream)
{
    const float* loc     = (const float*)d_in[0];
    const float* conf    = (const float*)d_in[1];
    const float* targets = (const float*)d_in[2];
    const float* priors  = (const float*)d_in[3];
    float* out = (float*)d_out;

    const int N = in_sizes[3] / 4;
    const int BN = in_sizes[0] / 4;
    const int B = BN / N;
    const int NOBJ = in_sizes[2] / (B * 5);
    const int SLICES = 8;
    const int CHUNK = (N + SLICES - 1) / SLICES;
    const int TPB = (N + 511) / 512;     // 512-row tiles per batch
    const int BPB = 6;                   // 768 blocks = 3/CU (43KB LDS)

    // workspace layout
    char* w = (char*)d_ws;
    float*    lc_ws   = (float*)w;                         size_t off = (size_t)BN * 4;
    float*    bpi_val = (float*)(w + off);                 off += (size_t)B * SLICES * 16 * 4;
    int*      bpi_idx = (int*)(w + off);                   off += (size_t)B * SLICES * 16 * 4;
    int*      num_pos = (int*)(w + off);                   off += (size_t)B * 4;
    float*    accB    = (float*)(w + off);                 off += (size_t)B * 2 * 4;
    float*    acc     = (float*)(w + off);                 off += 16;
    unsigned* done    = (unsigned*)(w + off);              off += 16;

    dim3 gA(SLICES, B);
    kA_best_prior<<<gA, 256, 0, stream>>>(targets, priors, bpi_val, bpi_idx,
                                          num_pos, accB, acc, done, N, NOBJ, SLICES, CHUNK, B);

    kB_main<<<B * BPB, 256, 0, stream>>>(loc, conf, targets, priors, bpi_val, bpi_idx,
                                         lc_ws, num_pos, accB, N, NOBJ, SLICES, TPB, BPB);

    kC_topk<<<B, 1024, 0, stream>>>(lc_ws, num_pos, accB, acc, done, out, N, B);
}